// Round 7
// baseline (105.539 us; speedup 1.0000x reference)
//
#include <hip/hip_runtime.h>
#include <hip/hip_fp16.h>

#define HH 256
#define WW 704
#define DD 64
#define CC 3
#define BB 2
#define HWN (HH * WW)       // 180224

#define TY 8                // out-tile rows
#define TX 16               // out-tile cols
#define RY0 12              // q0 region rows (tile + 2*2 halo)
#define RX0 20              // q0 region cols
#define NP0 (RY0 * RX0)     // 240
#define RY1 10              // q1 region rows (tile + 2*1 halo)
#define RX1 18              // q1 region cols
#define NP1 (RY1 * RX1)     // 180
#define NTX (WW / TX)       // 44
#define NTY (HH / TY)       // 32
#define NTILES (NTX * NTY)  // 1408 (divisible by 8 -> bijective XCD swizzle)

static constexpr float INV2Z2 = 1.0f / (2.0f * 1e-3f * 1e-3f);

// ---------------------------------------------------------------------------
// Affinity, 4 px per thread (float4): kaff[b,k,n] = ws*exp(-sum_c(uc-c)^2/2z^2)
// Zero-pad semantics: out-of-image tap value u = 0 (so d = -center).
// ---------------------------------------------------------------------------
__global__ __launch_bounds__(256) void affinity_kernel(
    const float* __restrict__ color, const float* __restrict__ wsp,
    float* __restrict__ kaff)
{
    int q = blockIdx.x * 256 + threadIdx.x;   // 0 .. HWN/4-1
    int b = blockIdx.y;
    int n0 = q * 4;
    int h = n0 / WW, w0 = n0 - h * WW;        // w0 multiple of 4
    float wsv = wsp[0];

    bool hm = h > 0, hp = h < HH - 1;
    bool wm = w0 > 0, wp = w0 + 4 < WW;
    int oN = hm ? -WW : 0, oS = hp ? WW : 0;  // clamped (values masked)
    int dl = wm ? -1 : 0, dr = wp ? 4 : 3;
    float rowm = hm ? 1.f : 0.f, rowp = hp ? 1.f : 0.f;
    float colm = wm ? 1.f : 0.f, colp = wp ? 1.f : 0.f;

    const float* cbase = color + (size_t)b * CC * HWN + n0;

    float ss[9][4];
#pragma unroll
    for (int t9 = 0; t9 < 9; ++t9)
#pragma unroll
        for (int j = 0; j < 4; ++j) ss[t9][j] = 0.f;

#pragma unroll
    for (int ch = 0; ch < 3; ++ch) {
        const float* cc = cbase + (size_t)ch * HWN;
        float4 C0 = *(const float4*)cc;
        float4 Cn = *(const float4*)(cc + oN);
        float4 Cs = *(const float4*)(cc + oS);
        float lN = cc[oN + dl], rN = cc[oN + dr];
        float l0 = cc[dl],      r0 = cc[dr];
        float lS = cc[oS + dl], rS = cc[oS + dr];
        // zero-pad masks
        Cn.x *= rowm; Cn.y *= rowm; Cn.z *= rowm; Cn.w *= rowm;
        Cs.x *= rowp; Cs.y *= rowp; Cs.z *= rowp; Cs.w *= rowp;
        lN *= rowm * colm; rN *= rowm * colp;
        l0 *= colm;        r0 *= colp;
        lS *= rowp * colm; rS *= rowp * colp;

        float wN[6]  = {lN, Cn.x, Cn.y, Cn.z, Cn.w, rN};
        float wC[6]  = {l0, C0.x, C0.y, C0.z, C0.w, r0};
        float wS[6]  = {lS, Cs.x, Cs.y, Cs.z, Cs.w, rS};
        float c4[4]  = {C0.x, C0.y, C0.z, C0.w};
#pragma unroll
        for (int dw = 0; dw < 3; ++dw)
#pragma unroll
            for (int j = 0; j < 4; ++j) {
                float d;
                d = wN[j + dw] - c4[j]; ss[0 + dw][j] += d * d;
                d = wC[j + dw] - c4[j]; ss[3 + dw][j] += d * d;
                d = wS[j + dw] - c4[j]; ss[6 + dw][j] += d * d;
            }
    }

    float* kb = kaff + (size_t)b * 9 * HWN + n0;
#pragma unroll
    for (int t9 = 0; t9 < 9; ++t9) {
        float4 o;
        o.x = wsv * __expf(-ss[t9][0] * INV2Z2);
        o.y = wsv * __expf(-ss[t9][1] * INV2Z2);
        o.z = wsv * __expf(-ss[t9][2] * INV2Z2);
        o.w = wsv * __expf(-ss[t9][3] * INV2Z2);
        *(float4*)(kb + (size_t)t9 * HWN) = o;
    }
}

// ---------------------------------------------------------------------------
// bf16/f16 LDS helpers. Layout: px-major, 32 dwords (64 f16 ch) per px, XOR
// swizzle on dword index: dw(p,q) = p*32 + (q ^ ((p&7)<<2)). Same permutation
// on store and load -> correctness independent of the mixing.
// ---------------------------------------------------------------------------
__device__ __forceinline__ void acc_tap(const unsigned* q, int p0, int cg,
                                        __half2 kh, __half2* tv2) {
    int ia = p0 * 32 + ((cg * 8) ^ ((p0 & 7) << 2));
    int ib = ia ^ 4;
    const __half2* qa = (const __half2*)&q[ia];  // ch 16cg+0..7  (pairs)
    const __half2* qb = (const __half2*)&q[ib];  // ch 16cg+8..15 (pairs)
    tv2[0] = __hfma2(kh, qa[0], tv2[0]);
    tv2[1] = __hfma2(kh, qa[1], tv2[1]);
    tv2[2] = __hfma2(kh, qa[2], tv2[2]);
    tv2[3] = __hfma2(kh, qa[3], tv2[3]);
    tv2[4] = __hfma2(kh, qb[0], tv2[4]);
    tv2[5] = __hfma2(kh, qb[1], tv2[5]);
    tv2[6] = __hfma2(kh, qb[2], tv2[6]);
    tv2[7] = __hfma2(kh, qb[3], tv2[7]);
}

__device__ __forceinline__ void st_px(unsigned* q, int p, int cg,
                                      const float* u, float scale) {
    int ia = p * 32 + ((cg * 8) ^ ((p & 7) << 2));
    int ib = ia ^ 4;
    __half2* qa = (__half2*)&q[ia];
    __half2* qb = (__half2*)&q[ib];
    qa[0] = __floats2half2_rn(u[0]  * scale, u[1]  * scale);
    qa[1] = __floats2half2_rn(u[2]  * scale, u[3]  * scale);
    qa[2] = __floats2half2_rn(u[4]  * scale, u[5]  * scale);
    qa[3] = __floats2half2_rn(u[6]  * scale, u[7]  * scale);
    qb[0] = __floats2half2_rn(u[8]  * scale, u[9]  * scale);
    qb[1] = __floats2half2_rn(u[10] * scale, u[11] * scale);
    qb[2] = __floats2half2_rn(u[12] * scale, u[13] * scale);
    qb[3] = __floats2half2_rn(u[14] * scale, u[15] * scale);
}

// 4-way exclusive prefix + totals over channel-groups (shfl partners at
// pxl+16g share the same task id -> divergence-safe in partial rounds)
__device__ __forceinline__ void scan4(float Aloc, float Bloc, int pxl, int cg,
                                      float& Ar, float& Br, float& T, float& E) {
    float A0 = __shfl(Aloc, pxl),      A1 = __shfl(Aloc, pxl + 16),
          A2 = __shfl(Aloc, pxl + 32), A3 = __shfl(Aloc, pxl + 48);
    float B0 = __shfl(Bloc, pxl),      B1 = __shfl(Bloc, pxl + 16),
          B2 = __shfl(Bloc, pxl + 32), B3 = __shfl(Bloc, pxl + 48);
    T = A0 + A1 + A2 + A3;  E = B0 + B1 + B2 + B3;
    Ar = 0.f; Br = 0.f;
    if (cg > 0) { Ar += A0; Br += B0; }
    if (cg > 1) { Ar += A1; Br += B1; }
    if (cg > 2) { Ar += A2; Br += B2; }
}

// tv[i] = t[e] -> exp(logit - q_hat); returns 1/sum over all 64 ch
__device__ __forceinline__ float finish_px(float* tv, const float* lgv,
                                           int pxl, int cg) {
    float Aloc = 0.f, Bloc = 0.f;
#pragma unroll
    for (int i = 0; i < 16; ++i) {
        float e = (float)(cg * 16 + i);
        Aloc += tv[i]; Bloc += e * tv[i];
    }
    float Ar, Br, T, E;
    scan4(Aloc, Bloc, pxl, cg, Ar, Br, T, E);
    float s = 0.f;
#pragma unroll
    for (int i = 0; i < 16; ++i) {
        float e = (float)(cg * 16 + i);
        Ar += tv[i]; Br += e * tv[i];
        float v = lgv[i] - (2.f * (e * Ar - Br) + E - e * T);
        tv[i] = __expf(v); s += tv[i];
    }
    s += __shfl_xor(s, 16);
    s += __shfl_xor(s, 32);
    return 1.f / s;
}

__device__ __forceinline__ void load_k(const float* kfb, int n, int gy, int gx,
                                       float* k) {
#pragma unroll
    for (int j = 0; j < 9; ++j) k[j] = kfb[(size_t)j * HWN + n];
    if (gy <= 0)      { k[0] = k[1] = k[2] = 0.f; }
    if (gy >= HH - 1) { k[6] = k[7] = k[8] = 0.f; }
    if (gx <= 0)      { k[0] = k[3] = k[6] = 0.f; }
    if (gx >= WW - 1) { k[2] = k[5] = k[8] = 0.f; }
}

// 9-tap stencil from an LDS q-region into tv[16] (f32), via packed f16 FMA
__device__ __forceinline__ void stencil9(const unsigned* qs, int rowstride,
                                         int py, int px, int cg,
                                         const float* k, float* tv) {
    __half2 tv2[8];
#pragma unroll
    for (int j = 0; j < 8; ++j) tv2[j] = __float2half2_rn(0.f);
    int base = (py + 1) * rowstride + (px + 1);
#pragma unroll
    for (int tap = 0; tap < 9; ++tap) {
        int dy = tap / 3 - 1, dx = tap - (tap / 3) * 3 - 1;
        acc_tap(qs, base + dy * rowstride + dx, cg, __float2half2_rn(k[tap]), tv2);
    }
#pragma unroll
    for (int j = 0; j < 8; ++j) {
        float2 f = __half22float2(tv2[j]);
        tv[2 * j] = f.x; tv[2 * j + 1] = f.y;
    }
}

// ---------------------------------------------------------------------------
// Fused CRF per 8x16 out-tile (task = 1 px, 4 lanes x 16 ch):
//   P0: q0 = softmax(logits) on 12x20 -> LDS f16
//   P1: q1 = iter(q0) on 10x18 -> LDS f16
//   P2: q2 = iter(q1) on 8x16 -> global
// Task->px mapping uses 16-wide strips so each 16-lane group covers aligned
// px runs (bank-conflict-free LDS, fully-coalesced 64B global runs).
// k[9] and lgv[16] are loaded at the top of each task body so their global
// latency hides under the LDS stencil.
// ---------------------------------------------------------------------------
__global__ __launch_bounds__(256) void fused_crf_kernel(
    const float* __restrict__ logits, const float* __restrict__ kaff,
    float* __restrict__ qout)
{
    __shared__ unsigned q0s[NP0 * 32];   // 30,720 B
    __shared__ unsigned q1s[NP1 * 32];   // 23,040 B

    const int t = threadIdx.x;
    const int lane = t & 63;
    const int wv = t >> 6;          // 0..3
    const int pxl = lane & 15;
    const int cg = lane >> 4;       // channels [16cg, 16cg+16)
    const int b = blockIdx.y;

    const int bid = blockIdx.x;     // XCD swizzle (1408 % 8 == 0 -> bijective)
    const int pb = (bid & 7) * (NTILES / 8) + (bid >> 3);
    const int tyr = pb / NTX, txc = pb - tyr * NTX;
    const int y0 = tyr * TY, x0 = txc * TX;

    const float* lgb = logits + ((size_t)b * DD + cg * 16) * HWN;
    const float* kfb = kaff + (size_t)b * 9 * HWN;

    // ---------------- P0: q0 = softmax(logits) on 12x20 ----------------
    for (int r = 0; r < 4; ++r) {
        int id = r * 64 + wv * 16 + pxl;
        if (id < NP0) {
            int py, px;
            if (id < 192) { py = id >> 4; px = id & 15; }
            else { int qq = id - 192; py = qq >> 2; px = 16 + (qq & 3); }
            int p = py * RX0 + px;
            int gy = min(max(y0 - 2 + py, 0), HH - 1);
            int gx = min(max(x0 - 2 + px, 0), WW - 1);
            const float* lg = lgb + gy * WW + gx;
            float v[16];
            float s = 0.f;
#pragma unroll
            for (int i = 0; i < 16; ++i) {
                v[i] = __expf(lg[(size_t)i * HWN]);
                s += v[i];
            }
            s += __shfl_xor(s, 16);
            s += __shfl_xor(s, 32);
            st_px(q0s, p, cg, v, 1.0f / s);
        }
    }
    __syncthreads();

    // ---------------- P1: q1 = iter(q0) on 10x18 ----------------
    for (int r = 0; r < 3; ++r) {
        int id = r * 64 + wv * 16 + pxl;
        if (id < NP1) {
            int py, px;
            if (id < 160) { py = id >> 4; px = id & 15; }
            else { int qq = id - 160; py = qq >> 1; px = 16 + (qq & 1); }
            int p = py * RX1 + px;
            int gy = y0 - 1 + py, gx = x0 - 1 + px;   // may be out of image
            int cy = min(max(gy, 0), HH - 1), cx = min(max(gx, 0), WW - 1);
            int n = cy * WW + cx;

            float k[9];
            load_k(kfb, n, gy, gx, k);
            const float* lgn = lgb + n;
            float lgv[16];
#pragma unroll
            for (int i = 0; i < 16; ++i) lgv[i] = lgn[(size_t)i * HWN];

            float tv[16];
            stencil9(q0s, RX0, py, px, cg, k, tv);
            float inv = finish_px(tv, lgv, pxl, cg);
            st_px(q1s, p, cg, tv, inv);
        }
    }
    __syncthreads();

    // ---------------- P2: q2 = iter(q1) -> global, 8x16 ----------------
    for (int r = 0; r < 2; ++r) {
        int id = r * 64 + wv * 16 + pxl;     // 0..127, all valid
        int py = id >> 4, px = id & 15;
        int gy = y0 + py, gx = x0 + px;      // always in image
        int n = gy * WW + gx;

        float k[9];
        load_k(kfb, n, gy, gx, k);
        const float* lgn = lgb + n;
        float lgv[16];
#pragma unroll
        for (int i = 0; i < 16; ++i) lgv[i] = lgn[(size_t)i * HWN];

        float tv[16];
        stencil9(q1s, RX1, py, px, cg, k, tv);
        float inv = finish_px(tv, lgv, pxl, cg);

        float* qo = qout + ((size_t)b * DD + cg * 16) * HWN + n;
#pragma unroll
        for (int i = 0; i < 16; ++i) qo[(size_t)i * HWN] = tv[i] * inv;
    }
}

// ---------------------------------------------------------------------------
extern "C" void kernel_launch(void* const* d_in, const int* in_sizes, int n_in,
                              void* d_out, int out_size, void* d_ws, size_t ws_size,
                              hipStream_t stream) {
    const float* color  = (const float*)d_in[0];
    // d_in[1] = feats: unused by the forward pass
    const float* logits = (const float*)d_in[2];
    const float* wsp    = (const float*)d_in[3];

    float* q_out = (float*)d_out;
    float* kaff  = (float*)d_ws;          // [B,9,HW] ~13 MB

    dim3 gridA(HWN / 4 / 256, BB);        // 4 px per thread
    affinity_kernel<<<gridA, 256, 0, stream>>>(color, wsp, kaff);

    dim3 gridF(NTILES, BB);               // 1408 tiles x 2 batches
    fused_crf_kernel<<<gridF, 256, 0, stream>>>(logits, kaff, q_out);
}